// Round 9
// baseline (798.984 us; speedup 1.0000x reference)
//
#include <hip/hip_runtime.h>

// W8A16 GEMM: out[m,n] = scale[n] * sum_k x[m,k]*Wint[n,k] + bias[n]
// M=8192, N=11008, K=4096. Device dtypes: x f32, W int32, scales f32, bias f32, out f32.
// Round 9: (a) vmcnt waits only at P4/P8 (m201 pattern; vmcnt(4), traced RAW/WAR),
// (b) MFMA 16x16x32 -> 32x32x16 (+15% pipe ceiling, m119: 2495 vs 2176 TF).
// A/B frag: row=lane&31, k=(lane>>5)*8+e; C/D: col=lane&31, row=(reg&3)+8*(reg>>2)+4*(lane>>5).
#define M_DIM 8192
#define N_DIM 11008
#define K_DIM 4096
#define K_TILES 64   // K / 64

typedef __bf16 bf16x8 __attribute__((ext_vector_type(8)));
typedef float  f32x4  __attribute__((ext_vector_type(4)));
typedef float  f32x16 __attribute__((ext_vector_type(16)));
typedef int    i32x4  __attribute__((ext_vector_type(4)));
typedef unsigned short u16x8 __attribute__((ext_vector_type(8)));

__device__ __forceinline__ unsigned short f2bf_rne(float f) {
  unsigned u = __float_as_uint(f);
  u += 0x7fffu + ((u >> 16) & 1u);
  return (unsigned short)(u >> 16);
}
__device__ __forceinline__ unsigned short i2bf(int v) {
  float f = (float)v;  // |v| <= 127: exact in bf16
  return (unsigned short)(__float_as_uint(f) >> 16);
}
__device__ __forceinline__ void async_copy16(void* lds_dst, const void* g_src) {
  __builtin_amdgcn_global_load_lds(
      (const __attribute__((address_space(1))) void*)g_src,
      (__attribute__((address_space(3))) void*)lds_dst,
      16, 0, 0);
}

// ---------------- prepass: W int32 -> bf16 (exact) ----------------
__global__ __launch_bounds__(256)
void dequant_w_kernel(const int* __restrict__ W, unsigned short* __restrict__ Wb) {
  const int NG = N_DIM * K_DIM / 8;
  for (int g = blockIdx.x * 256 + threadIdx.x; g < NG; g += gridDim.x * 256) {
    const int* p = W + (size_t)g * 8;
    i32x4 w0 = *(const i32x4*)p;
    i32x4 w1 = *(const i32x4*)(p + 4);
    u16x8 o;
    #pragma unroll
    for (int e = 0; e < 4; ++e) { o[e] = i2bf(w0[e]); o[e + 4] = i2bf(w1[e]); }
    *(u16x8*)(Wb + (size_t)g * 8) = o;
  }
}

// ---------------- prepass: X f32 -> bf16 (RNE) ----------------
__global__ __launch_bounds__(256)
void conv_x_kernel(const float* __restrict__ X, unsigned short* __restrict__ Xb) {
  const int NG = M_DIM * K_DIM / 8;
  for (int g = blockIdx.x * 256 + threadIdx.x; g < NG; g += gridDim.x * 256) {
    const float* p = X + (size_t)g * 8;
    f32x4 a0 = *(const f32x4*)p;
    f32x4 a1 = *(const f32x4*)(p + 4);
    u16x8 o;
    #pragma unroll
    for (int e = 0; e < 4; ++e) { o[e] = f2bf_rne(a0[e]); o[e + 4] = f2bf_rne(a1[e]); }
    *(u16x8*)(Xb + (size_t)g * 8) = o;
  }
}

// ---------------- main: 256x256 8-phase bf16 GEMM, 32x32x16 MFMA ----------------
// LDS: buf b at b*32768 (A) / +16384 (B) ushorts. Tile [256 rows][64 k],
// swizzle LDS[row][col ^ ((row&7)<<3)] = global[row][col] (inverse-swizzled
// global source, linear global_load_lds dest, swizzled ds_read).
// Wave tile 128x64: 4 row-tiles of 32 (global row-tile 2*ii+wr), 2 col-tiles of 32
// (global col-tile 4*NQ+wc). Quadrant (MQ,NQ): row-tiles {2MQ,2MQ+1}, col-tile NQ.
// Snake 00->01->11->10; A reused across NQ-flip, B (both NQ) across MQ-flip.
// vmcnt(4) at P4: retires all tile-v units (prev-P7/P8 + this-P1/P2);
// vmcnt(4) at P8: retires all tile-(u+2) units (staged P3..P6). All reads are
// >= 1 barrier behind retirement. Drain: P4=4, P5=2, P6=0 (unit-traced).
__global__ __launch_bounds__(512, 2)
void w8a16_main_kernel(const unsigned short* __restrict__ Xb,  // [M][K] bf16
                       const unsigned short* __restrict__ Wb,  // [N][K] bf16
                       const float* __restrict__ S,
                       const float* __restrict__ Bv,
                       float*       __restrict__ O)
{
  __shared__ unsigned short sh[65536];  // 128 KB

  const int tid  = threadIdx.x;
  const int lane = tid & 63;
  const int wid  = tid >> 6;       // 8 waves
  const int wr   = wid >> 2;       // 0..1  (M)
  const int wc   = wid & 3;        // 0..3  (N)

  // T1: bijective XCD swizzle, 1376 = 8 x 172.
  const int swz = (blockIdx.x & 7) * 172 + (blockIdx.x >> 3);
  const int bm = swz / 43, bn = swz % 43;
  const int row0 = bm * 256, col0 = bn * 256;

  f32x16 acc[4][2] = {};   // [row-tile ii][col-tile NQ]

  // Persistent fragment registers
  bf16x8 af[2][4];   // A frags for current MQ: [iq][kslice]
  bf16x8 bq[2][4];   // B frags: [NQ][kslice], both NQ live

  // ---- fragment-read addressing (3-bit swizzle; per-k-slice XOR) ----
  const int r31 = lane & 31;
  const int kg  = (lane >> 5) * 8;        // {0,8}
  const int swl = (lane & 7) << 3;        // row&7 == lane&7 for all frag rows
  const int off0 = r31 * 64 + ((kg)      ^ swl);
  const int off1 = r31 * 64 + ((16 + kg) ^ swl);
  const int off2 = r31 * 64 + ((32 + kg) ^ swl);
  const int off3 = r31 * 64 + ((48 + kg) ^ swl);

  // ---- stage addressing: chunk = wid*2+q; within-half row = chunk*8 + lane/8 ----
  const int ch0 = wid * 2;
  const int sr0 = ch0 * 8 + (lane >> 3);                 // 0..127
  const int sr1 = sr0 + 8;                               // (sr1&7)==(sr0&7)
  const int sc0 = ((lane & 7) * 8) ^ ((sr0 & 7) << 3);   // inverse-swizzled src col
  const int sc1 = ((lane & 7) * 8) ^ ((sr1 & 7) << 3);
  const unsigned short* Xs0 = Xb + (size_t)(row0 + sr0) * K_DIM + sc0;
  const unsigned short* Xs1 = Xb + (size_t)(row0 + sr1) * K_DIM + sc1;
  const unsigned short* Ws0 = Wb + (size_t)(col0 + sr0) * K_DIM + sc0;
  const unsigned short* Ws1 = Wb + (size_t)(col0 + sr1) * K_DIM + sc1;
  const size_t HALF = (size_t)128 * K_DIM;

#define STAGE_X(st, h) do { \
    unsigned short* _d = sh + ((st) & 1) * 32768 + (h) * 8192 + ch0 * 512; \
    async_copy16(_d,       Xs0 + (size_t)(h) * HALF + (size_t)(st) * 64); \
    async_copy16(_d + 512, Xs1 + (size_t)(h) * HALF + (size_t)(st) * 64); \
  } while (0)
#define STAGE_W(st, h) do { \
    unsigned short* _d = sh + ((st) & 1) * 32768 + 16384 + (h) * 8192 + ch0 * 512; \
    async_copy16(_d,       Ws0 + (size_t)(h) * HALF + (size_t)(st) * 64); \
    async_copy16(_d + 512, Ws1 + (size_t)(h) * HALF + (size_t)(st) * 64); \
  } while (0)
#define VM(N) asm volatile("s_waitcnt vmcnt(" #N ")" ::: "memory")

#define PHASE(tt, MQ, NQ, DOA, DOB, STAGE_STMT, WAIT_STMT) do { \
    const unsigned short* Ab = sh + ((tt) & 1) * 32768; \
    const unsigned short* Bb = Ab + 16384; \
    if (DOA) { \
      _Pragma("unroll") \
      for (int iq = 0; iq < 2; ++iq) { \
        const int abase = (4 * (MQ) + 2 * iq + wr) * 2048; \
        af[iq][0] = *(const bf16x8*)&Ab[abase + off0]; \
        af[iq][1] = *(const bf16x8*)&Ab[abase + off1]; \
        af[iq][2] = *(const bf16x8*)&Ab[abase + off2]; \
        af[iq][3] = *(const bf16x8*)&Ab[abase + off3]; \
      } \
    } \
    if (DOB) { \
      const int bbase = (4 * (NQ) + wc) * 2048; \
      bq[NQ][0] = *(const bf16x8*)&Bb[bbase + off0]; \
      bq[NQ][1] = *(const bf16x8*)&Bb[bbase + off1]; \
      bq[NQ][2] = *(const bf16x8*)&Bb[bbase + off2]; \
      bq[NQ][3] = *(const bf16x8*)&Bb[bbase + off3]; \
    } \
    STAGE_STMT; \
    WAIT_STMT; \
    __builtin_amdgcn_s_barrier(); \
    __builtin_amdgcn_s_setprio(1); \
    _Pragma("unroll") \
    for (int ks = 0; ks < 4; ++ks) \
      _Pragma("unroll") \
      for (int iq = 0; iq < 2; ++iq) \
        acc[2*(MQ)+iq][NQ] = __builtin_amdgcn_mfma_f32_32x32x16_bf16(af[iq][ks], bq[NQ][ks], acc[2*(MQ)+iq][NQ], 0, 0, 0); \
    __builtin_amdgcn_s_setprio(0); \
    __builtin_amdgcn_s_barrier(); \
    __builtin_amdgcn_sched_barrier(0); \
  } while (0)

  // ---- prologue: 6 units (12 loads); vmcnt(4) retires units 1-4 (read P1-P3);
  //      units 5,6 (X(1,0),W(1,0)) retire at first P4 wait, read P5. ----
  STAGE_X(0, 0); STAGE_W(0, 0); STAGE_W(0, 1); STAGE_X(0, 1);
  STAGE_X(1, 0); STAGE_W(1, 0);
  VM(4);
  __builtin_amdgcn_s_barrier();

  // ---- main loop: iterations 0..30; waits only at P4/P8 ----
  for (int i = 0; i < K_TILES / 2 - 1; ++i) {
    const int u = 2 * i, v = 2 * i + 1;
    PHASE(u, 0, 0, 1, 1, { STAGE_W(v, 1); },     {});
    PHASE(u, 0, 1, 0, 1, { STAGE_X(v, 1); },     {});
    PHASE(u, 1, 1, 1, 0, { STAGE_X(u + 2, 0); }, {});
    PHASE(u, 1, 0, 0, 0, { STAGE_W(u + 2, 0); }, { VM(4); });
    PHASE(v, 0, 0, 1, 1, { STAGE_W(u + 2, 1); }, {});
    PHASE(v, 0, 1, 0, 1, { STAGE_X(u + 2, 1); }, {});
    PHASE(v, 1, 1, 1, 0, { STAGE_X(v + 2, 0); }, {});
    PHASE(v, 1, 0, 0, 0, { STAGE_W(v + 2, 0); }, { VM(4); });
  }

  // ---- peeled last iteration (u=62, v=63): drains 4/2/0 (unit-traced) ----
  {
    const int u = K_TILES - 2, v = K_TILES - 1;
    PHASE(u, 0, 0, 1, 1, { STAGE_W(v, 1); }, {});
    PHASE(u, 0, 1, 0, 1, { STAGE_X(v, 1); }, {});
    PHASE(u, 1, 1, 1, 0, {},                 {});
    PHASE(u, 1, 0, 0, 0, {},                 { VM(4); });
    PHASE(v, 0, 0, 1, 1, {},                 { VM(2); });
    PHASE(v, 0, 1, 0, 1, {},                 { VM(0); });
    PHASE(v, 1, 1, 1, 0, {},                 {});
    PHASE(v, 1, 0, 0, 0, {},                 {});
  }

  // ---- epilogue: scale + bias, store f32 ----
  // C/D 32x32 layout (m74/m101): col = lane&31, row = (reg&3)+8*(reg>>2)+4*(lane>>5)
  const int rbase = (lane >> 5) * 4;
  #pragma unroll
  for (int nq = 0; nq < 2; ++nq) {
    const int ocol = col0 + (4 * nq + wc) * 32 + r31;
    const float s  = S[ocol];
    const float bb = Bv[ocol];
    #pragma unroll
    for (int ii = 0; ii < 4; ++ii) {
      const int orow0 = row0 + (2 * ii + wr) * 32 + rbase;
      #pragma unroll
      for (int reg = 0; reg < 16; ++reg) {
        const int orow = orow0 + (reg & 3) + 8 * (reg >> 2);
        O[(size_t)orow * N_DIM + ocol] = acc[ii][nq][reg] * s + bb;
      }
    }
  }
#undef PHASE
#undef VM
#undef STAGE_X
#undef STAGE_W
}

// ---------------- fallback (round-3 kernel, verified) ----------------
#define FB_BM 128
#define FB_BK 32
#define PITCH 40
__global__ __launch_bounds__(256)
void w8a16_fallback_kernel(const float* __restrict__ X, const int* __restrict__ W,
                           const float* __restrict__ S, const float* __restrict__ Bv,
                           float* __restrict__ O)
{
  __shared__ unsigned short As[FB_BM * PITCH];
  __shared__ unsigned short Bs[FB_BM * PITCH];
  const int tid = threadIdx.x, lane = tid & 63, wid = tid >> 6;
  const int wr = wid >> 1, wc = wid & 1;
  const int p = blockIdx.x, xcd = p & 7, seq = p >> 3;
  const int bn_idx = seq >> 3, by_idx = xcd * 8 + (seq & 7);
  const int row0 = by_idx * FB_BM, col0 = bn_idx * FB_BM;
  f32x4 acc[4][4] = {};
  const int st_row = tid >> 1, st_kc = (tid & 1) * 16;
  const float* xsrc = X + (size_t)(row0 + st_row) * K_DIM + st_kc;
  const int*   wsrc = W + (size_t)(col0 + st_row) * K_DIM + st_kc;
  unsigned short* adst = &As[st_row * PITCH + st_kc];
  unsigned short* bdst = &Bs[st_row * PITCH + st_kc];
  const int fr = lane & 15, fk = (lane >> 4) * 8;
  for (int kt = 0; kt < K_DIM; kt += FB_BK) {
    f32x4 a0 = *(const f32x4*)(xsrc + kt);
    f32x4 a1 = *(const f32x4*)(xsrc + kt + 4);
    f32x4 a2 = *(const f32x4*)(xsrc + kt + 8);
    f32x4 a3 = *(const f32x4*)(xsrc + kt + 12);
    i32x4 w0 = *(const i32x4*)(wsrc + kt);
    i32x4 w1 = *(const i32x4*)(wsrc + kt + 4);
    i32x4 w2 = *(const i32x4*)(wsrc + kt + 8);
    i32x4 w3 = *(const i32x4*)(wsrc + kt + 12);
    u16x8 pa0, pa1, pb0, pb1;
    #pragma unroll
    for (int e = 0; e < 4; ++e) {
      pa0[e] = f2bf_rne(a0[e]); pa0[e+4] = f2bf_rne(a1[e]);
      pa1[e] = f2bf_rne(a2[e]); pa1[e+4] = f2bf_rne(a3[e]);
      pb0[e] = i2bf(w0[e]);     pb0[e+4] = i2bf(w1[e]);
      pb1[e] = i2bf(w2[e]);     pb1[e+4] = i2bf(w3[e]);
    }
    __syncthreads();
    *(u16x8*)(adst) = pa0; *(u16x8*)(adst + 8) = pa1;
    *(u16x8*)(bdst) = pb0; *(u16x8*)(bdst + 8) = pb1;
    __syncthreads();
    bf16x8 af2[4], bfr[4];
    #pragma unroll
    for (int i = 0; i < 4; ++i)
      af2[i] = *(const bf16x8*)&As[(wr * 64 + i * 16 + fr) * PITCH + fk];
    #pragma unroll
    for (int j = 0; j < 4; ++j)
      bfr[j] = *(const bf16x8*)&Bs[(wc * 64 + j * 16 + fr) * PITCH + fk];
    #pragma unroll
    for (int i = 0; i < 4; ++i)
      #pragma unroll
      for (int j = 0; j < 4; ++j)
        acc[i][j] = __builtin_amdgcn_mfma_f32_16x16x32_bf16(af2[i], bfr[j], acc[i][j], 0, 0, 0);
  }
  const int erow = (lane >> 4) * 4, ecol = lane & 15;
  #pragma unroll
  for (int j = 0; j < 4; ++j) {
    const int col = col0 + wc * 64 + j * 16 + ecol;
    const float s = S[col], bb = Bv[col];
    #pragma unroll
    for (int i = 0; i < 4; ++i) {
      const int rbase = row0 + wr * 64 + i * 16 + erow;
      #pragma unroll
      for (int e = 0; e < 4; ++e)
        O[(size_t)(rbase + e) * N_DIM + col] = acc[i][j][e] * s + bb;
    }
  }
}

extern "C" void kernel_launch(void* const* d_in, const int* in_sizes, int n_in,
                              void* d_out, int out_size, void* d_ws, size_t ws_size,
                              hipStream_t stream) {
  const float* x  = (const float*)d_in[0];
  const int*   w  = (const int*)d_in[1];
  const float* sc = (const float*)d_in[2];
  const float* bi = (const float*)d_in[3];
  float* out = (float*)d_out;

  const size_t w_elems = (size_t)N_DIM * K_DIM;
  const size_t x_elems = (size_t)M_DIM * K_DIM;
  const size_t need = (w_elems + x_elems) * sizeof(unsigned short);

  if (ws_size >= need) {
    unsigned short* Wb = (unsigned short*)d_ws;
    unsigned short* Xb = Wb + w_elems;
    dequant_w_kernel<<<2048, 256, 0, stream>>>(w, Wb);
    conv_x_kernel<<<2048, 256, 0, stream>>>(x, Xb);
    const int grid = (M_DIM / 256) * (N_DIM / 256);  // 32 * 43 = 1376
    w8a16_main_kernel<<<grid, 512, 0, stream>>>(Xb, Wb, sc, bi, out);
  } else {
    const int grid = (M_DIM / FB_BM) * (N_DIM / FB_BM);
    w8a16_fallback_kernel<<<grid, 256, 0, stream>>>(x, w, sc, bi, out);
  }
}

// Round 10
// 723.062 us; speedup vs baseline: 1.1050x; 1.1050x over previous
//
#include <hip/hip_runtime.h>

// W8A16 GEMM: out[m,n] = scale[n] * sum_k x[m,k]*Wint[n,k] + bias[n]
// M=8192, N=11008, K=4096. Device dtypes: x f32, W int32, scales f32, bias f32, out f32.
// Round 10: revert to round-8 structure (16x16x32 MFMA, snake reuse, per-phase
// counted vmcnt, 0 bank conflicts) + ONE change: stage slots shifted 1 phase
// earlier and vmcnt 8 -> 10 (prefetch age 4 -> 5 phases ~ 1550 cyc > HBM latency).
#define M_DIM 8192
#define N_DIM 11008
#define K_DIM 4096
#define K_TILES 64   // K / 64

typedef __bf16 bf16x8 __attribute__((ext_vector_type(8)));
typedef float  f32x4  __attribute__((ext_vector_type(4)));
typedef int    i32x4  __attribute__((ext_vector_type(4)));
typedef unsigned short u16x8 __attribute__((ext_vector_type(8)));

__device__ __forceinline__ unsigned short f2bf_rne(float f) {
  unsigned u = __float_as_uint(f);
  u += 0x7fffu + ((u >> 16) & 1u);
  return (unsigned short)(u >> 16);
}
__device__ __forceinline__ unsigned short i2bf(int v) {
  float f = (float)v;  // |v| <= 127: exact in bf16
  return (unsigned short)(__float_as_uint(f) >> 16);
}
__device__ __forceinline__ void async_copy16(void* lds_dst, const void* g_src) {
  __builtin_amdgcn_global_load_lds(
      (const __attribute__((address_space(1))) void*)g_src,
      (__attribute__((address_space(3))) void*)lds_dst,
      16, 0, 0);
}

// ---------------- prepass: W int32 -> bf16 (exact) ----------------
__global__ __launch_bounds__(256)
void dequant_w_kernel(const int* __restrict__ W, unsigned short* __restrict__ Wb) {
  const int NG = N_DIM * K_DIM / 8;
  for (int g = blockIdx.x * 256 + threadIdx.x; g < NG; g += gridDim.x * 256) {
    const int* p = W + (size_t)g * 8;
    i32x4 w0 = *(const i32x4*)p;
    i32x4 w1 = *(const i32x4*)(p + 4);
    u16x8 o;
    #pragma unroll
    for (int e = 0; e < 4; ++e) { o[e] = i2bf(w0[e]); o[e + 4] = i2bf(w1[e]); }
    *(u16x8*)(Wb + (size_t)g * 8) = o;
  }
}

// ---------------- prepass: X f32 -> bf16 (RNE) ----------------
__global__ __launch_bounds__(256)
void conv_x_kernel(const float* __restrict__ X, unsigned short* __restrict__ Xb) {
  const int NG = M_DIM * K_DIM / 8;
  for (int g = blockIdx.x * 256 + threadIdx.x; g < NG; g += gridDim.x * 256) {
    const float* p = X + (size_t)g * 8;
    f32x4 a0 = *(const f32x4*)p;
    f32x4 a1 = *(const f32x4*)(p + 4);
    u16x8 o;
    #pragma unroll
    for (int e = 0; e < 4; ++e) { o[e] = f2bf_rne(a0[e]); o[e + 4] = f2bf_rne(a1[e]); }
    *(u16x8*)(Xb + (size_t)g * 8) = o;
  }
}

// ---------------- main: 256x256 8-phase bf16 GEMM ----------------
// LDS: buf b at b*32768 (A) / +16384 (B). Tile [256 rows][64 k] ushort,
// swizzle LDS[row][col ^ ((row&7)<<3)] = global[row][col] (inverse-swizzled
// global source, linear global_load_lds dest, swizzled ds_read).
// Snake order per tile: (MQ,NQ) = (0,0)->(0,1)->(1,1)->(1,0); A-frags reused
// across NQ-switch, B-frags (both halves in regs) across MQ-switch.
// Pipeline (1 stage-unit/phase, VM(10) per phase): unit staged at phase p is
// retired at p+5's wait, first LDS read at p+7. WAR: every overwritten region's
// last read completes before its phase-end barrier (reads feed same-phase MFMA,
// lgkmcnt forces completion pre-barrier); stage issues >= 1 barrier later.
// Stage slots: P1:X(v,1) P2:X(u+2,0) P3:W(u+2,0) P4:W(u+2,1)
//              P5:X(u+2,1) P6:X(v+2,0) P7:W(v+2,0) P8:W(v+2,1)
// Tail peeled: stage X(63,1) at P1; waits 10,8,-,4,2,0 (unit-traced).
__global__ __launch_bounds__(512, 2)
void w8a16_main_kernel(const unsigned short* __restrict__ Xb,  // [M][K] bf16
                       const unsigned short* __restrict__ Wb,  // [N][K] bf16
                       const float* __restrict__ S,
                       const float* __restrict__ Bv,
                       float*       __restrict__ O)
{
  __shared__ unsigned short sh[65536];  // 128 KB

  const int tid  = threadIdx.x;
  const int lane = tid & 63;
  const int wid  = tid >> 6;       // 8 waves
  const int wr   = wid >> 2;       // 0..1  (M)
  const int wc   = wid & 3;        // 0..3  (N)

  // T1: bijective XCD swizzle, 1376 = 8 x 172.
  const int swz = (blockIdx.x & 7) * 172 + (blockIdx.x >> 3);
  const int bm = swz / 43, bn = swz % 43;
  const int row0 = bm * 256, col0 = bn * 256;

  f32x4 acc[8][4] = {};

  // Persistent fragment registers (reused across phases)
  bf16x8 af[4][2];      // A-half fragments for current MQ [ii][kslice]
  bf16x8 bq[2][2][2];   // B fragments [NQ][jj][kslice], both halves live

  // ---- fragment-read addressing (3-bit swizzle; per-k-slot XOR) ----
  const int fr   = lane & 15;
  const int fkk  = (lane >> 4) * 8;            // {0,8,16,24}
  const int sw_r = (fr & 7) << 3;              // swizzle (ushorts)
  const int aoff0 = fr * 64 + (fkk ^ sw_r);          // k-slot 0
  const int aoff1 = fr * 64 + ((fkk + 32) ^ sw_r);   // k-slot 1
  const int boff0 = aoff0;
  const int boff1 = aoff1;

  // ---- stage addressing: chunk = wid*2+q; within-half row = chunk*8 + lane/8 ----
  const int ch0 = wid * 2;
  const int sr0 = ch0 * 8 + (lane >> 3);                 // 0..127
  const int sr1 = sr0 + 8;                               // (sr1&7)==(sr0&7)
  const int sc0 = ((lane & 7) * 8) ^ ((sr0 & 7) << 3);   // inverse-swizzled src col
  const int sc1 = ((lane & 7) * 8) ^ ((sr1 & 7) << 3);
  const unsigned short* Xs0 = Xb + (size_t)(row0 + sr0) * K_DIM + sc0;
  const unsigned short* Xs1 = Xb + (size_t)(row0 + sr1) * K_DIM + sc1;
  const unsigned short* Ws0 = Wb + (size_t)(col0 + sr0) * K_DIM + sc0;
  const unsigned short* Ws1 = Wb + (size_t)(col0 + sr1) * K_DIM + sc1;
  const size_t HALF = (size_t)128 * K_DIM;

#define STAGE_X(st, h) do { \
    unsigned short* _d = sh + ((st) & 1) * 32768 + (h) * 8192 + ch0 * 512; \
    async_copy16(_d,       Xs0 + (size_t)(h) * HALF + (size_t)(st) * 64); \
    async_copy16(_d + 512, Xs1 + (size_t)(h) * HALF + (size_t)(st) * 64); \
  } while (0)
#define STAGE_W(st, h) do { \
    unsigned short* _d = sh + ((st) & 1) * 32768 + 16384 + (h) * 8192 + ch0 * 512; \
    async_copy16(_d,       Ws0 + (size_t)(h) * HALF + (size_t)(st) * 64); \
    async_copy16(_d + 512, Ws1 + (size_t)(h) * HALF + (size_t)(st) * 64); \
  } while (0)
#define VM(N) asm volatile("s_waitcnt vmcnt(" #N ")" ::: "memory")

#define PHASE(tt, MQ, NQ, DOA, DOB, STAGE_STMT, WAIT_STMT) do { \
    const unsigned short* Ab = sh + ((tt) & 1) * 32768; \
    const unsigned short* Bb = Ab + 16384; \
    if (DOA) { \
      _Pragma("unroll") \
      for (int ii = 0; ii < 4; ++ii) { \
        af[ii][0] = *(const bf16x8*)&Ab[(2 * (4 * (MQ) + ii) + wr) * 1024 + aoff0]; \
        af[ii][1] = *(const bf16x8*)&Ab[(2 * (4 * (MQ) + ii) + wr) * 1024 + aoff1]; \
      } \
    } \
    if (DOB) { \
      _Pragma("unroll") \
      for (int jj = 0; jj < 2; ++jj) { \
        bq[NQ][jj][0] = *(const bf16x8*)&Bb[(4 * (2 * (NQ) + jj) + wc) * 1024 + boff0]; \
        bq[NQ][jj][1] = *(const bf16x8*)&Bb[(4 * (2 * (NQ) + jj) + wc) * 1024 + boff1]; \
      } \
    } \
    STAGE_STMT; \
    WAIT_STMT; \
    __builtin_amdgcn_s_barrier(); \
    __builtin_amdgcn_s_setprio(1); \
    _Pragma("unroll") \
    for (int ii = 0; ii < 4; ++ii) \
      _Pragma("unroll") \
      for (int jj = 0; jj < 2; ++jj) { \
        acc[4*(MQ)+ii][2*(NQ)+jj] = __builtin_amdgcn_mfma_f32_16x16x32_bf16(af[ii][0], bq[NQ][jj][0], acc[4*(MQ)+ii][2*(NQ)+jj], 0, 0, 0); \
        acc[4*(MQ)+ii][2*(NQ)+jj] = __builtin_amdgcn_mfma_f32_16x16x32_bf16(af[ii][1], bq[NQ][jj][1], acc[4*(MQ)+ii][2*(NQ)+jj], 0, 0, 0); \
      } \
    __builtin_amdgcn_s_setprio(0); \
    __builtin_amdgcn_s_barrier(); \
    __builtin_amdgcn_sched_barrier(0); \
  } while (0)

  // ---- prologue: 7 units (14 loads) in read order; VM(10) retires units 1-2
  //      (X(0,0), W(0,0)) for P1's reads. Units 3..7 retire at P1..P5 waits. ----
  STAGE_X(0, 0); STAGE_W(0, 0); STAGE_W(0, 1); STAGE_X(0, 1);
  STAGE_X(1, 0); STAGE_W(1, 0); STAGE_W(1, 1);
  VM(10);
  __builtin_amdgcn_s_barrier();

  // ---- main loop: iterations 0..30; 1 stage/phase, VM(10) per phase ----
  for (int i = 0; i < K_TILES / 2 - 1; ++i) {
    const int u = 2 * i, v = 2 * i + 1;
    PHASE(u, 0, 0, 1, 1, { STAGE_X(v, 1); },     { VM(10); });
    PHASE(u, 0, 1, 0, 1, { STAGE_X(u + 2, 0); }, { VM(10); });
    PHASE(u, 1, 1, 1, 0, { STAGE_W(u + 2, 0); }, { VM(10); });
    PHASE(u, 1, 0, 0, 0, { STAGE_W(u + 2, 1); }, { VM(10); });
    PHASE(v, 0, 0, 1, 1, { STAGE_X(u + 2, 1); }, { VM(10); });
    PHASE(v, 0, 1, 0, 1, { STAGE_X(v + 2, 0); }, { VM(10); });
    PHASE(v, 1, 1, 1, 0, { STAGE_W(v + 2, 0); }, { VM(10); });
    PHASE(v, 1, 0, 0, 0, { STAGE_W(v + 2, 1); }, { VM(10); });
  }

  // ---- peeled last iteration (u=62, v=63): stage X(63,1) at P1; graded
  //      drains 10,8,-,4,2,0 (unit-traced: W(62,1)@P1, X(62,1)@P2,
  //      X(63,0)+W(63,0)@P4, W(63,1)@P5, X(63,1)@P6). ----
  {
    const int u = K_TILES - 2, v = K_TILES - 1;
    PHASE(u, 0, 0, 1, 1, { STAGE_X(v, 1); }, { VM(10); });
    PHASE(u, 0, 1, 0, 1, {},                 { VM(8);  });
    PHASE(u, 1, 1, 1, 0, {},                 {});
    PHASE(u, 1, 0, 0, 0, {},                 { VM(4);  });
    PHASE(v, 0, 0, 1, 1, {},                 { VM(2);  });
    PHASE(v, 0, 1, 0, 1, {},                 { VM(0);  });
    PHASE(v, 1, 1, 1, 0, {},                 {});
    PHASE(v, 1, 0, 0, 0, {},                 {});
  }

  // ---- epilogue: scale + bias, store f32 ----
  // C/D layout (m89): col = lane&15, row = (lane>>4)*4 + e
  const int erow = (lane >> 4) * 4;
  const int ecol = lane & 15;
  #pragma unroll
  for (int j = 0; j < 4; ++j) {
    const int ocol = col0 + (4 * j + wc) * 16 + ecol;
    const float s  = S[ocol];
    const float bb = Bv[ocol];
    #pragma unroll
    for (int ii = 0; ii < 8; ++ii) {
      const int orow = row0 + (2 * ii + wr) * 16 + erow;
      #pragma unroll
      for (int e = 0; e < 4; ++e)
        O[(size_t)(orow + e) * N_DIM + ocol] = acc[ii][j][e] * s + bb;
    }
  }
#undef PHASE
#undef VM
#undef STAGE_X
#undef STAGE_W
}

// ---------------- fallback (round-3 kernel, verified) ----------------
#define FB_BM 128
#define FB_BK 32
#define PITCH 40
__global__ __launch_bounds__(256)
void w8a16_fallback_kernel(const float* __restrict__ X, const int* __restrict__ W,
                           const float* __restrict__ S, const float* __restrict__ Bv,
                           float* __restrict__ O)
{
  __shared__ unsigned short As[FB_BM * PITCH];
  __shared__ unsigned short Bs[FB_BM * PITCH];
  const int tid = threadIdx.x, lane = tid & 63, wid = tid >> 6;
  const int wr = wid >> 1, wc = wid & 1;
  const int p = blockIdx.x, xcd = p & 7, seq = p >> 3;
  const int bn_idx = seq >> 3, by_idx = xcd * 8 + (seq & 7);
  const int row0 = by_idx * FB_BM, col0 = bn_idx * FB_BM;
  f32x4 acc[4][4] = {};
  const int st_row = tid >> 1, st_kc = (tid & 1) * 16;
  const float* xsrc = X + (size_t)(row0 + st_row) * K_DIM + st_kc;
  const int*   wsrc = W + (size_t)(col0 + st_row) * K_DIM + st_kc;
  unsigned short* adst = &As[st_row * PITCH + st_kc];
  unsigned short* bdst = &Bs[st_row * PITCH + st_kc];
  const int fr = lane & 15, fk = (lane >> 4) * 8;
  for (int kt = 0; kt < K_DIM; kt += FB_BK) {
    f32x4 a0 = *(const f32x4*)(xsrc + kt);
    f32x4 a1 = *(const f32x4*)(xsrc + kt + 4);
    f32x4 a2 = *(const f32x4*)(xsrc + kt + 8);
    f32x4 a3 = *(const f32x4*)(xsrc + kt + 12);
    i32x4 w0 = *(const i32x4*)(wsrc + kt);
    i32x4 w1 = *(const i32x4*)(wsrc + kt + 4);
    i32x4 w2 = *(const i32x4*)(wsrc + kt + 8);
    i32x4 w3 = *(const i32x4*)(wsrc + kt + 12);
    u16x8 pa0, pa1, pb0, pb1;
    #pragma unroll
    for (int e = 0; e < 4; ++e) {
      pa0[e] = f2bf_rne(a0[e]); pa0[e+4] = f2bf_rne(a1[e]);
      pa1[e] = f2bf_rne(a2[e]); pa1[e+4] = f2bf_rne(a3[e]);
      pb0[e] = i2bf(w0[e]);     pb0[e+4] = i2bf(w1[e]);
      pb1[e] = i2bf(w2[e]);     pb1[e+4] = i2bf(w3[e]);
    }
    __syncthreads();
    *(u16x8*)(adst) = pa0; *(u16x8*)(adst + 8) = pa1;
    *(u16x8*)(bdst) = pb0; *(u16x8*)(bdst + 8) = pb1;
    __syncthreads();
    bf16x8 af2[4], bfr[4];
    #pragma unroll
    for (int i = 0; i < 4; ++i)
      af2[i] = *(const bf16x8*)&As[(wr * 64 + i * 16 + fr) * PITCH + fk];
    #pragma unroll
    for (int j = 0; j < 4; ++j)
      bfr[j] = *(const bf16x8*)&Bs[(wc * 64 + j * 16 + fr) * PITCH + fk];
    #pragma unroll
    for (int i = 0; i < 4; ++i)
      #pragma unroll
      for (int j = 0; j < 4; ++j)
        acc[i][j] = __builtin_amdgcn_mfma_f32_16x16x32_bf16(af2[i], bfr[j], acc[i][j], 0, 0, 0);
  }
  const int erow = (lane >> 4) * 4, ecol = lane & 15;
  #pragma unroll
  for (int j = 0; j < 4; ++j) {
    const int col = col0 + wc * 64 + j * 16 + ecol;
    const float s = S[col], bb = Bv[col];
    #pragma unroll
    for (int i = 0; i < 4; ++i) {
      const int rbase = row0 + wr * 64 + i * 16 + erow;
      #pragma unroll
      for (int e = 0; e < 4; ++e)
        O[(size_t)(rbase + e) * N_DIM + col] = acc[i][j][e] * s + bb;
    }
  }
}

extern "C" void kernel_launch(void* const* d_in, const int* in_sizes, int n_in,
                              void* d_out, int out_size, void* d_ws, size_t ws_size,
                              hipStream_t stream) {
  const float* x  = (const float*)d_in[0];
  const int*   w  = (const int*)d_in[1];
  const float* sc = (const float*)d_in[2];
  const float* bi = (const float*)d_in[3];
  float* out = (float*)d_out;

  const size_t w_elems = (size_t)N_DIM * K_DIM;
  const size_t x_elems = (size_t)M_DIM * K_DIM;
  const size_t need = (w_elems + x_elems) * sizeof(unsigned short);

  if (ws_size >= need) {
    unsigned short* Wb = (unsigned short*)d_ws;
    unsigned short* Xb = Wb + w_elems;
    dequant_w_kernel<<<2048, 256, 0, stream>>>(w, Wb);
    conv_x_kernel<<<2048, 256, 0, stream>>>(x, Xb);
    const int grid = (M_DIM / 256) * (N_DIM / 256);  // 32 * 43 = 1376
    w8a16_main_kernel<<<grid, 512, 0, stream>>>(Xb, Wb, sc, bi, out);
  } else {
    const int grid = (M_DIM / FB_BM) * (N_DIM / FB_BM);
    w8a16_fallback_kernel<<<grid, 256, 0, stream>>>(x, w, sc, bi, out);
  }
}

// Round 11
// 721.156 us; speedup vs baseline: 1.1079x; 1.0026x over previous
//
#include <hip/hip_runtime.h>

// W8A16 GEMM: out[m,n] = scale[n] * sum_k x[m,k]*Wint[n,k] + bias[n]
// M=8192, N=11008, K=4096. Device dtypes: x f32, W int32, scales f32, bias f32, out f32.
// Round 11: round-10 pipeline unchanged; TAIL SPLIT: grid 1376 = 256*5.375 leaves
// ~11% ramp-down (96 CUs x 6 blocks). Last 96 tiles (1280..1375) are split into
// 192 half-K blocks (atomicAdd f32, zero-prepass for that region, bias in half 0).
// f32 add is bitwise-commutative and each element gets exactly 2 adds -> deterministic.
#define M_DIM 8192
#define N_DIM 11008
#define K_DIM 4096
#define K_TILES 64      // K / 64
#define FULL_TILES 1280 // tiles handled as single full-K blocks
#define NTILES 1376     // 32 * 43

typedef __bf16 bf16x8 __attribute__((ext_vector_type(8)));
typedef float  f32x4  __attribute__((ext_vector_type(4)));
typedef int    i32x4  __attribute__((ext_vector_type(4)));
typedef unsigned short u16x8 __attribute__((ext_vector_type(8)));

__device__ __forceinline__ unsigned short f2bf_rne(float f) {
  unsigned u = __float_as_uint(f);
  u += 0x7fffu + ((u >> 16) & 1u);
  return (unsigned short)(u >> 16);
}
__device__ __forceinline__ unsigned short i2bf(int v) {
  float f = (float)v;  // |v| <= 127: exact in bf16
  return (unsigned short)(__float_as_uint(f) >> 16);
}
__device__ __forceinline__ void async_copy16(void* lds_dst, const void* g_src) {
  __builtin_amdgcn_global_load_lds(
      (const __attribute__((address_space(1))) void*)g_src,
      (__attribute__((address_space(3))) void*)lds_dst,
      16, 0, 0);
}

// ---------------- prepass: W int32 -> bf16 (exact) ----------------
__global__ __launch_bounds__(256)
void dequant_w_kernel(const int* __restrict__ W, unsigned short* __restrict__ Wb) {
  const int NG = N_DIM * K_DIM / 8;
  for (int g = blockIdx.x * 256 + threadIdx.x; g < NG; g += gridDim.x * 256) {
    const int* p = W + (size_t)g * 8;
    i32x4 w0 = *(const i32x4*)p;
    i32x4 w1 = *(const i32x4*)(p + 4);
    u16x8 o;
    #pragma unroll
    for (int e = 0; e < 4; ++e) { o[e] = i2bf(w0[e]); o[e + 4] = i2bf(w1[e]); }
    *(u16x8*)(Wb + (size_t)g * 8) = o;
  }
}

// ---------------- prepass: X f32 -> bf16 (RNE) ----------------
__global__ __launch_bounds__(256)
void conv_x_kernel(const float* __restrict__ X, unsigned short* __restrict__ Xb) {
  const int NG = M_DIM * K_DIM / 8;
  for (int g = blockIdx.x * 256 + threadIdx.x; g < NG; g += gridDim.x * 256) {
    const float* p = X + (size_t)g * 8;
    f32x4 a0 = *(const f32x4*)p;
    f32x4 a1 = *(const f32x4*)(p + 4);
    u16x8 o;
    #pragma unroll
    for (int e = 0; e < 4; ++e) { o[e] = f2bf_rne(a0[e]); o[e + 4] = f2bf_rne(a1[e]); }
    *(u16x8*)(Xb + (size_t)g * 8) = o;
  }
}

// ---------------- swizzle helper (tile id -> output tile coords) ----------------
__device__ __forceinline__ void tile_coords(int tile, int& row0, int& col0) {
  // T1: bijective XCD swizzle, 1376 = 8 x 172.
  const int swz = (tile & 7) * 172 + (tile >> 3);
  const int bm = swz / 43, bn = swz % 43;
  row0 = bm * 256; col0 = bn * 256;
}

// ---------------- zero-prepass for the atomic (split) tile region ----------------
__global__ __launch_bounds__(256)
void zero_partial_kernel(float* __restrict__ O) {
  int row0, col0;
  tile_coords(FULL_TILES + blockIdx.x, row0, col0);
  // 256x256 f32 rect: 256 threads; thread t zeroes row r cols in float4 chunks.
  const int tidx = threadIdx.x;
  for (int r = 0; r < 256; ++r) {
    float* rowp = O + (size_t)(row0 + r) * N_DIM + col0;
    // 256 floats = 64 float4; 256 threads stride over them (64 < 256 -> t<64 works)
    for (int c4 = tidx; c4 < 64; c4 += 256)
      *(f32x4*)(rowp + c4 * 4) = f32x4{0.f, 0.f, 0.f, 0.f};
  }
}

// ---------------- main: 256x256 8-phase bf16 GEMM ----------------
// Pipeline identical to round 10 (16x16x32 MFMA, snake reuse, 3-bit XOR swizzle,
// per-phase VM(10), peeled tail 10/8/-/4/2/0). New: block -> (tile, k0, nkt, mode):
//   bid < 1280: full tile, k0=0, nkt=64, store epilogue.
//   bid >= 1280: idx=bid-1280; tile=1280+idx/2; half=idx&1; k0=half*32; nkt=32;
//                epilogue atomicAdd (bias only in half 0).
__global__ __launch_bounds__(512, 2)
void w8a16_main_kernel(const unsigned short* __restrict__ Xb,  // [M][K] bf16
                       const unsigned short* __restrict__ Wb,  // [N][K] bf16
                       const float* __restrict__ S,
                       const float* __restrict__ Bv,
                       float*       __restrict__ O)
{
  __shared__ unsigned short sh[65536];  // 128 KB

  const int tid  = threadIdx.x;
  const int lane = tid & 63;
  const int wid  = tid >> 6;       // 8 waves
  const int wr   = wid >> 2;       // 0..1  (M)
  const int wc   = wid & 3;        // 0..3  (N)

  const int bid = blockIdx.x;
  int tile, half, nkt, partial;
  if (bid < FULL_TILES) { tile = bid; half = 0; nkt = K_TILES; partial = 0; }
  else {
    const int idx = bid - FULL_TILES;
    tile = FULL_TILES + (idx >> 1);
    half = idx & 1;
    nkt  = K_TILES / 2;
    partial = 1;
  }
  int row0, col0;
  tile_coords(tile, row0, col0);
  const size_t kbase = (size_t)half * (K_TILES / 2) * 64;  // element offset in K

  f32x4 acc[8][4] = {};

  // Persistent fragment registers (reused across phases)
  bf16x8 af[4][2];      // A-half fragments for current MQ [ii][kslice]
  bf16x8 bq[2][2][2];   // B fragments [NQ][jj][kslice], both halves live

  // ---- fragment-read addressing (3-bit swizzle; per-k-slot XOR) ----
  const int fr   = lane & 15;
  const int fkk  = (lane >> 4) * 8;            // {0,8,16,24}
  const int sw_r = (fr & 7) << 3;              // swizzle (ushorts)
  const int aoff0 = fr * 64 + (fkk ^ sw_r);          // k-slot 0
  const int aoff1 = fr * 64 + ((fkk + 32) ^ sw_r);   // k-slot 1
  const int boff0 = aoff0;
  const int boff1 = aoff1;

  // ---- stage addressing: chunk = wid*2+q; within-half row = chunk*8 + lane/8 ----
  const int ch0 = wid * 2;
  const int sr0 = ch0 * 8 + (lane >> 3);                 // 0..127
  const int sr1 = sr0 + 8;                               // (sr1&7)==(sr0&7)
  const int sc0 = ((lane & 7) * 8) ^ ((sr0 & 7) << 3);   // inverse-swizzled src col
  const int sc1 = ((lane & 7) * 8) ^ ((sr1 & 7) << 3);
  const unsigned short* Xs0 = Xb + (size_t)(row0 + sr0) * K_DIM + kbase + sc0;
  const unsigned short* Xs1 = Xb + (size_t)(row0 + sr1) * K_DIM + kbase + sc1;
  const unsigned short* Ws0 = Wb + (size_t)(col0 + sr0) * K_DIM + kbase + sc0;
  const unsigned short* Ws1 = Wb + (size_t)(col0 + sr1) * K_DIM + kbase + sc1;
  const size_t HALF = (size_t)128 * K_DIM;

#define STAGE_X(st, h) do { \
    unsigned short* _d = sh + ((st) & 1) * 32768 + (h) * 8192 + ch0 * 512; \
    async_copy16(_d,       Xs0 + (size_t)(h) * HALF + (size_t)(st) * 64); \
    async_copy16(_d + 512, Xs1 + (size_t)(h) * HALF + (size_t)(st) * 64); \
  } while (0)
#define STAGE_W(st, h) do { \
    unsigned short* _d = sh + ((st) & 1) * 32768 + 16384 + (h) * 8192 + ch0 * 512; \
    async_copy16(_d,       Ws0 + (size_t)(h) * HALF + (size_t)(st) * 64); \
    async_copy16(_d + 512, Ws1 + (size_t)(h) * HALF + (size_t)(st) * 64); \
  } while (0)
#define VM(N) asm volatile("s_waitcnt vmcnt(" #N ")" ::: "memory")

#define PHASE(tt, MQ, NQ, DOA, DOB, STAGE_STMT, WAIT_STMT) do { \
    const unsigned short* Ab = sh + ((tt) & 1) * 32768; \
    const unsigned short* Bb = Ab + 16384; \
    if (DOA) { \
      _Pragma("unroll") \
      for (int ii = 0; ii < 4; ++ii) { \
        af[ii][0] = *(const bf16x8*)&Ab[(2 * (4 * (MQ) + ii) + wr) * 1024 + aoff0]; \
        af[ii][1] = *(const bf16x8*)&Ab[(2 * (4 * (MQ) + ii) + wr) * 1024 + aoff1]; \
      } \
    } \
    if (DOB) { \
      _Pragma("unroll") \
      for (int jj = 0; jj < 2; ++jj) { \
        bq[NQ][jj][0] = *(const bf16x8*)&Bb[(4 * (2 * (NQ) + jj) + wc) * 1024 + boff0]; \
        bq[NQ][jj][1] = *(const bf16x8*)&Bb[(4 * (2 * (NQ) + jj) + wc) * 1024 + boff1]; \
      } \
    } \
    STAGE_STMT; \
    WAIT_STMT; \
    __builtin_amdgcn_s_barrier(); \
    __builtin_amdgcn_s_setprio(1); \
    _Pragma("unroll") \
    for (int ii = 0; ii < 4; ++ii) \
      _Pragma("unroll") \
      for (int jj = 0; jj < 2; ++jj) { \
        acc[4*(MQ)+ii][2*(NQ)+jj] = __builtin_amdgcn_mfma_f32_16x16x32_bf16(af[ii][0], bq[NQ][jj][0], acc[4*(MQ)+ii][2*(NQ)+jj], 0, 0, 0); \
        acc[4*(MQ)+ii][2*(NQ)+jj] = __builtin_amdgcn_mfma_f32_16x16x32_bf16(af[ii][1], bq[NQ][jj][1], acc[4*(MQ)+ii][2*(NQ)+jj], 0, 0, 0); \
      } \
    __builtin_amdgcn_s_setprio(0); \
    __builtin_amdgcn_s_barrier(); \
    __builtin_amdgcn_sched_barrier(0); \
  } while (0)

  // ---- prologue: 7 units (14 loads) in read order; VM(10) retires units 1-2
  //      (X(0,0), W(0,0)) for P1's reads. Units 3..7 retire at P1..P5 waits. ----
  STAGE_X(0, 0); STAGE_W(0, 0); STAGE_W(0, 1); STAGE_X(0, 1);
  STAGE_X(1, 0); STAGE_W(1, 0); STAGE_W(1, 1);
  VM(10);
  __builtin_amdgcn_s_barrier();

  // ---- main loop: iterations 0..nkt/2-2; 1 stage/phase, VM(10) per phase ----
  for (int i = 0; i < nkt / 2 - 1; ++i) {
    const int u = 2 * i, v = 2 * i + 1;
    PHASE(u, 0, 0, 1, 1, { STAGE_X(v, 1); },     { VM(10); });
    PHASE(u, 0, 1, 0, 1, { STAGE_X(u + 2, 0); }, { VM(10); });
    PHASE(u, 1, 1, 1, 0, { STAGE_W(u + 2, 0); }, { VM(10); });
    PHASE(u, 1, 0, 0, 0, { STAGE_W(u + 2, 1); }, { VM(10); });
    PHASE(v, 0, 0, 1, 1, { STAGE_X(u + 2, 1); }, { VM(10); });
    PHASE(v, 0, 1, 0, 1, { STAGE_X(v + 2, 0); }, { VM(10); });
    PHASE(v, 1, 1, 1, 0, { STAGE_W(v + 2, 0); }, { VM(10); });
    PHASE(v, 1, 0, 0, 0, { STAGE_W(v + 2, 1); }, { VM(10); });
  }

  // ---- peeled last iteration (u=nkt-2, v=nkt-1): stage X(v,1) at P1; graded
  //      drains 10,8,-,4,2,0 (unit-traced; identical outstanding counts for
  //      nkt=64 and nkt=32 since the steady state is the same). ----
  {
    const int u = nkt - 2, v = nkt - 1;
    PHASE(u, 0, 0, 1, 1, { STAGE_X(v, 1); }, { VM(10); });
    PHASE(u, 0, 1, 0, 1, {},                 { VM(8);  });
    PHASE(u, 1, 1, 1, 0, {},                 {});
    PHASE(u, 1, 0, 0, 0, {},                 { VM(4);  });
    PHASE(v, 0, 0, 1, 1, {},                 { VM(2);  });
    PHASE(v, 0, 1, 0, 1, {},                 { VM(0);  });
    PHASE(v, 1, 1, 1, 0, {},                 {});
    PHASE(v, 1, 0, 0, 0, {},                 {});
  }

  // ---- epilogue: scale + bias; full tiles store, split tiles atomicAdd ----
  // C/D layout (m89): col = lane&15, row = (lane>>4)*4 + e
  const int erow = (lane >> 4) * 4;
  const int ecol = lane & 15;
  #pragma unroll
  for (int j = 0; j < 4; ++j) {
    const int ocol = col0 + (4 * j + wc) * 16 + ecol;
    const float s  = S[ocol];
    const float bb = (partial && half == 1) ? 0.0f : Bv[ocol];
    #pragma unroll
    for (int ii = 0; ii < 8; ++ii) {
      const int orow = row0 + (2 * ii + wr) * 16 + erow;
      #pragma unroll
      for (int e = 0; e < 4; ++e) {
        const float v = acc[ii][j][e] * s + bb;
        float* dst = &O[(size_t)(orow + e) * N_DIM + ocol];
        if (partial) atomicAdd(dst, v);
        else         *dst = v;
      }
    }
  }
#undef PHASE
#undef VM
#undef STAGE_X
#undef STAGE_W
}

// ---------------- fallback (round-3 kernel, verified) ----------------
#define FB_BM 128
#define FB_BK 32
#define PITCH 40
__global__ __launch_bounds__(256)
void w8a16_fallback_kernel(const float* __restrict__ X, const int* __restrict__ W,
                           const float* __restrict__ S, const float* __restrict__ Bv,
                           float* __restrict__ O)
{
  __shared__ unsigned short As[FB_BM * PITCH];
  __shared__ unsigned short Bs[FB_BM * PITCH];
  const int tid = threadIdx.x, lane = tid & 63, wid = tid >> 6;
  const int wr = wid >> 1, wc = wid & 1;
  const int p = blockIdx.x, xcd = p & 7, seq = p >> 3;
  const int bn_idx = seq >> 3, by_idx = xcd * 8 + (seq & 7);
  const int row0 = by_idx * FB_BM, col0 = bn_idx * FB_BM;
  f32x4 acc[4][4] = {};
  const int st_row = tid >> 1, st_kc = (tid & 1) * 16;
  const float* xsrc = X + (size_t)(row0 + st_row) * K_DIM + st_kc;
  const int*   wsrc = W + (size_t)(col0 + st_row) * K_DIM + st_kc;
  unsigned short* adst = &As[st_row * PITCH + st_kc];
  unsigned short* bdst = &Bs[st_row * PITCH + st_kc];
  const int fr = lane & 15, fk = (lane >> 4) * 8;
  for (int kt = 0; kt < K_DIM; kt += FB_BK) {
    f32x4 a0 = *(const f32x4*)(xsrc + kt);
    f32x4 a1 = *(const f32x4*)(xsrc + kt + 4);
    f32x4 a2 = *(const f32x4*)(xsrc + kt + 8);
    f32x4 a3 = *(const f32x4*)(xsrc + kt + 12);
    i32x4 w0 = *(const i32x4*)(wsrc + kt);
    i32x4 w1 = *(const i32x4*)(wsrc + kt + 4);
    i32x4 w2 = *(const i32x4*)(wsrc + kt + 8);
    i32x4 w3 = *(const i32x4*)(wsrc + kt + 12);
    u16x8 pa0, pa1, pb0, pb1;
    #pragma unroll
    for (int e = 0; e < 4; ++e) {
      pa0[e] = f2bf_rne(a0[e]); pa0[e+4] = f2bf_rne(a1[e]);
      pa1[e] = f2bf_rne(a2[e]); pa1[e+4] = f2bf_rne(a3[e]);
      pb0[e] = i2bf(w0[e]);     pb0[e+4] = i2bf(w1[e]);
      pb1[e] = i2bf(w2[e]);     pb1[e+4] = i2bf(w3[e]);
    }
    __syncthreads();
    *(u16x8*)(adst) = pa0; *(u16x8*)(adst + 8) = pa1;
    *(u16x8*)(bdst) = pb0; *(u16x8*)(bdst + 8) = pb1;
    __syncthreads();
    bf16x8 af2[4], bfr[4];
    #pragma unroll
    for (int i = 0; i < 4; ++i)
      af2[i] = *(const bf16x8*)&As[(wr * 64 + i * 16 + fr) * PITCH + fk];
    #pragma unroll
    for (int j = 0; j < 4; ++j)
      bfr[j] = *(const bf16x8*)&Bs[(wc * 64 + j * 16 + fr) * PITCH + fk];
    #pragma unroll
    for (int i = 0; i < 4; ++i)
      #pragma unroll
      for (int j = 0; j < 4; ++j)
        acc[i][j] = __builtin_amdgcn_mfma_f32_16x16x32_bf16(af2[i], bfr[j], acc[i][j], 0, 0, 0);
  }
  const int erow = (lane >> 4) * 4, ecol = lane & 15;
  #pragma unroll
  for (int j = 0; j < 4; ++j) {
    const int col = col0 + wc * 64 + j * 16 + ecol;
    const float s = S[col], bb = Bv[col];
    #pragma unroll
    for (int i = 0; i < 4; ++i) {
      const int rbase = row0 + wr * 64 + i * 16 + erow;
      #pragma unroll
      for (int e = 0; e < 4; ++e)
        O[(size_t)(rbase + e) * N_DIM + col] = acc[i][j][e] * s + bb;
    }
  }
}

extern "C" void kernel_launch(void* const* d_in, const int* in_sizes, int n_in,
                              void* d_out, int out_size, void* d_ws, size_t ws_size,
                              hipStream_t stream) {
  const float* x  = (const float*)d_in[0];
  const int*   w  = (const int*)d_in[1];
  const float* sc = (const float*)d_in[2];
  const float* bi = (const float*)d_in[3];
  float* out = (float*)d_out;

  const size_t w_elems = (size_t)N_DIM * K_DIM;
  const size_t x_elems = (size_t)M_DIM * K_DIM;
  const size_t need = (w_elems + x_elems) * sizeof(unsigned short);

  if (ws_size >= need) {
    unsigned short* Wb = (unsigned short*)d_ws;
    unsigned short* Xb = Wb + w_elems;
    zero_partial_kernel<<<NTILES - FULL_TILES, 256, 0, stream>>>(out);
    dequant_w_kernel<<<2048, 256, 0, stream>>>(w, Wb);
    conv_x_kernel<<<2048, 256, 0, stream>>>(x, Xb);
    // grid: 1280 full-K blocks + 192 half-K blocks (last 96 tiles split in 2)
    const int grid = FULL_TILES + 2 * (NTILES - FULL_TILES);  // 1472
    w8a16_main_kernel<<<grid, 512, 0, stream>>>(Xb, Wb, sc, bi, out);
  } else {
    const int grid = (M_DIM / FB_BM) * (N_DIM / FB_BM);
    w8a16_fallback_kernel<<<grid, 256, 0, stream>>>(x, w, sc, bi, out);
  }
}

// Round 12
// 716.070 us; speedup vs baseline: 1.1158x; 1.0071x over previous
//
#include <hip/hip_runtime.h>

// W8A16 GEMM: out[m,n] = scale[n] * sum_k x[m,k]*Wint[n,k] + bias[n]
// M=8192, N=11008, K=4096. Device dtypes: x f32, W int32, scales f32, bias f32, out f32.
// Round 12: round-11 pipeline + split schedule unchanged; ONE fix: zero_partial
// was 75%-idle and row-serial (~30us for 25MB). Now flat grid-stride, all lanes
// active, coalesced f32x4 (~5us).
#define M_DIM 8192
#define N_DIM 11008
#define K_DIM 4096
#define K_TILES 64      // K / 64
#define FULL_TILES 1280 // tiles handled as single full-K blocks
#define NTILES 1376     // 32 * 43

typedef __bf16 bf16x8 __attribute__((ext_vector_type(8)));
typedef float  f32x4  __attribute__((ext_vector_type(4)));
typedef int    i32x4  __attribute__((ext_vector_type(4)));
typedef unsigned short u16x8 __attribute__((ext_vector_type(8)));

__device__ __forceinline__ unsigned short f2bf_rne(float f) {
  unsigned u = __float_as_uint(f);
  u += 0x7fffu + ((u >> 16) & 1u);
  return (unsigned short)(u >> 16);
}
__device__ __forceinline__ unsigned short i2bf(int v) {
  float f = (float)v;  // |v| <= 127: exact in bf16
  return (unsigned short)(__float_as_uint(f) >> 16);
}
__device__ __forceinline__ void async_copy16(void* lds_dst, const void* g_src) {
  __builtin_amdgcn_global_load_lds(
      (const __attribute__((address_space(1))) void*)g_src,
      (__attribute__((address_space(3))) void*)lds_dst,
      16, 0, 0);
}

// ---------------- prepass: W int32 -> bf16 (exact) ----------------
__global__ __launch_bounds__(256)
void dequant_w_kernel(const int* __restrict__ W, unsigned short* __restrict__ Wb) {
  const int NG = N_DIM * K_DIM / 8;
  for (int g = blockIdx.x * 256 + threadIdx.x; g < NG; g += gridDim.x * 256) {
    const int* p = W + (size_t)g * 8;
    i32x4 w0 = *(const i32x4*)p;
    i32x4 w1 = *(const i32x4*)(p + 4);
    u16x8 o;
    #pragma unroll
    for (int e = 0; e < 4; ++e) { o[e] = i2bf(w0[e]); o[e + 4] = i2bf(w1[e]); }
    *(u16x8*)(Wb + (size_t)g * 8) = o;
  }
}

// ---------------- prepass: X f32 -> bf16 (RNE) ----------------
__global__ __launch_bounds__(256)
void conv_x_kernel(const float* __restrict__ X, unsigned short* __restrict__ Xb) {
  const int NG = M_DIM * K_DIM / 8;
  for (int g = blockIdx.x * 256 + threadIdx.x; g < NG; g += gridDim.x * 256) {
    const float* p = X + (size_t)g * 8;
    f32x4 a0 = *(const f32x4*)p;
    f32x4 a1 = *(const f32x4*)(p + 4);
    u16x8 o;
    #pragma unroll
    for (int e = 0; e < 4; ++e) { o[e] = f2bf_rne(a0[e]); o[e + 4] = f2bf_rne(a1[e]); }
    *(u16x8*)(Xb + (size_t)g * 8) = o;
  }
}

// ---------------- swizzle helper (tile id -> output tile coords) ----------------
__device__ __forceinline__ void tile_coords(int tile, int& row0, int& col0) {
  // T1: bijective XCD swizzle, 1376 = 8 x 172.
  const int swz = (tile & 7) * 172 + (tile >> 3);
  const int bm = swz / 43, bn = swz % 43;
  row0 = bm * 256; col0 = bn * 256;
}

// ---------------- zero-prepass for the atomic (split) tile region ----------------
// Flat grid-stride over 96 tiles x 256 rows x 64 f32x4 chunks; all lanes active.
__global__ __launch_bounds__(256)
void zero_partial_kernel(float* __restrict__ O) {
  const int total = (NTILES - FULL_TILES) * 256 * 64;  // 1,572,864 f32x4
  for (int idx = blockIdx.x * 256 + threadIdx.x; idx < total; idx += gridDim.x * 256) {
    const int t   = idx >> 14;            // / (256*64)
    const int rem = idx & 16383;
    const int r   = rem >> 6;             // / 64
    const int c4  = rem & 63;
    int row0, col0;
    tile_coords(FULL_TILES + t, row0, col0);
    *(f32x4*)(O + (size_t)(row0 + r) * N_DIM + col0 + c4 * 4) = f32x4{0.f, 0.f, 0.f, 0.f};
  }
}

// ---------------- main: 256x256 8-phase bf16 GEMM ----------------
// Pipeline identical to rounds 10/11 (16x16x32 MFMA, snake reuse, 3-bit XOR
// swizzle, per-phase VM(10), peeled tail 10/8/-/4/2/0). Block -> (tile, half):
//   bid < 1280: full tile, nkt=64, store epilogue.
//   bid >= 1280: idx=bid-1280; tile=1280+idx/2; half=idx&1; nkt=32;
//                epilogue atomicAdd (bias only in half 0; region pre-zeroed).
__global__ __launch_bounds__(512, 2)
void w8a16_main_kernel(const unsigned short* __restrict__ Xb,  // [M][K] bf16
                       const unsigned short* __restrict__ Wb,  // [N][K] bf16
                       const float* __restrict__ S,
                       const float* __restrict__ Bv,
                       float*       __restrict__ O)
{
  __shared__ unsigned short sh[65536];  // 128 KB

  const int tid  = threadIdx.x;
  const int lane = tid & 63;
  const int wid  = tid >> 6;       // 8 waves
  const int wr   = wid >> 2;       // 0..1  (M)
  const int wc   = wid & 3;        // 0..3  (N)

  const int bid = blockIdx.x;
  int tile, half, nkt, partial;
  if (bid < FULL_TILES) { tile = bid; half = 0; nkt = K_TILES; partial = 0; }
  else {
    const int idx = bid - FULL_TILES;
    tile = FULL_TILES + (idx >> 1);
    half = idx & 1;
    nkt  = K_TILES / 2;
    partial = 1;
  }
  int row0, col0;
  tile_coords(tile, row0, col0);
  const size_t kbase = (size_t)half * (K_TILES / 2) * 64;  // element offset in K

  f32x4 acc[8][4] = {};

  // Persistent fragment registers (reused across phases)
  bf16x8 af[4][2];      // A-half fragments for current MQ [ii][kslice]
  bf16x8 bq[2][2][2];   // B fragments [NQ][jj][kslice], both halves live

  // ---- fragment-read addressing (3-bit swizzle; per-k-slot XOR) ----
  const int fr   = lane & 15;
  const int fkk  = (lane >> 4) * 8;            // {0,8,16,24}
  const int sw_r = (fr & 7) << 3;              // swizzle (ushorts)
  const int aoff0 = fr * 64 + (fkk ^ sw_r);          // k-slot 0
  const int aoff1 = fr * 64 + ((fkk + 32) ^ sw_r);   // k-slot 1
  const int boff0 = aoff0;
  const int boff1 = aoff1;

  // ---- stage addressing: chunk = wid*2+q; within-half row = chunk*8 + lane/8 ----
  const int ch0 = wid * 2;
  const int sr0 = ch0 * 8 + (lane >> 3);                 // 0..127
  const int sr1 = sr0 + 8;                               // (sr1&7)==(sr0&7)
  const int sc0 = ((lane & 7) * 8) ^ ((sr0 & 7) << 3);   // inverse-swizzled src col
  const int sc1 = ((lane & 7) * 8) ^ ((sr1 & 7) << 3);
  const unsigned short* Xs0 = Xb + (size_t)(row0 + sr0) * K_DIM + kbase + sc0;
  const unsigned short* Xs1 = Xb + (size_t)(row0 + sr1) * K_DIM + kbase + sc1;
  const unsigned short* Ws0 = Wb + (size_t)(col0 + sr0) * K_DIM + kbase + sc0;
  const unsigned short* Ws1 = Wb + (size_t)(col0 + sr1) * K_DIM + kbase + sc1;
  const size_t HALF = (size_t)128 * K_DIM;

#define STAGE_X(st, h) do { \
    unsigned short* _d = sh + ((st) & 1) * 32768 + (h) * 8192 + ch0 * 512; \
    async_copy16(_d,       Xs0 + (size_t)(h) * HALF + (size_t)(st) * 64); \
    async_copy16(_d + 512, Xs1 + (size_t)(h) * HALF + (size_t)(st) * 64); \
  } while (0)
#define STAGE_W(st, h) do { \
    unsigned short* _d = sh + ((st) & 1) * 32768 + 16384 + (h) * 8192 + ch0 * 512; \
    async_copy16(_d,       Ws0 + (size_t)(h) * HALF + (size_t)(st) * 64); \
    async_copy16(_d + 512, Ws1 + (size_t)(h) * HALF + (size_t)(st) * 64); \
  } while (0)
#define VM(N) asm volatile("s_waitcnt vmcnt(" #N ")" ::: "memory")

#define PHASE(tt, MQ, NQ, DOA, DOB, STAGE_STMT, WAIT_STMT) do { \
    const unsigned short* Ab = sh + ((tt) & 1) * 32768; \
    const unsigned short* Bb = Ab + 16384; \
    if (DOA) { \
      _Pragma("unroll") \
      for (int ii = 0; ii < 4; ++ii) { \
        af[ii][0] = *(const bf16x8*)&Ab[(2 * (4 * (MQ) + ii) + wr) * 1024 + aoff0]; \
        af[ii][1] = *(const bf16x8*)&Ab[(2 * (4 * (MQ) + ii) + wr) * 1024 + aoff1]; \
      } \
    } \
    if (DOB) { \
      _Pragma("unroll") \
      for (int jj = 0; jj < 2; ++jj) { \
        bq[NQ][jj][0] = *(const bf16x8*)&Bb[(4 * (2 * (NQ) + jj) + wc) * 1024 + boff0]; \
        bq[NQ][jj][1] = *(const bf16x8*)&Bb[(4 * (2 * (NQ) + jj) + wc) * 1024 + boff1]; \
      } \
    } \
    STAGE_STMT; \
    WAIT_STMT; \
    __builtin_amdgcn_s_barrier(); \
    __builtin_amdgcn_s_setprio(1); \
    _Pragma("unroll") \
    for (int ii = 0; ii < 4; ++ii) \
      _Pragma("unroll") \
      for (int jj = 0; jj < 2; ++jj) { \
        acc[4*(MQ)+ii][2*(NQ)+jj] = __builtin_amdgcn_mfma_f32_16x16x32_bf16(af[ii][0], bq[NQ][jj][0], acc[4*(MQ)+ii][2*(NQ)+jj], 0, 0, 0); \
        acc[4*(MQ)+ii][2*(NQ)+jj] = __builtin_amdgcn_mfma_f32_16x16x32_bf16(af[ii][1], bq[NQ][jj][1], acc[4*(MQ)+ii][2*(NQ)+jj], 0, 0, 0); \
      } \
    __builtin_amdgcn_s_setprio(0); \
    __builtin_amdgcn_s_barrier(); \
    __builtin_amdgcn_sched_barrier(0); \
  } while (0)

  // ---- prologue: 7 units (14 loads) in read order; VM(10) retires units 1-2
  //      (X(0,0), W(0,0)) for P1's reads. Units 3..7 retire at P1..P5 waits. ----
  STAGE_X(0, 0); STAGE_W(0, 0); STAGE_W(0, 1); STAGE_X(0, 1);
  STAGE_X(1, 0); STAGE_W(1, 0); STAGE_W(1, 1);
  VM(10);
  __builtin_amdgcn_s_barrier();

  // ---- main loop: iterations 0..nkt/2-2; 1 stage/phase, VM(10) per phase ----
  for (int i = 0; i < nkt / 2 - 1; ++i) {
    const int u = 2 * i, v = 2 * i + 1;
    PHASE(u, 0, 0, 1, 1, { STAGE_X(v, 1); },     { VM(10); });
    PHASE(u, 0, 1, 0, 1, { STAGE_X(u + 2, 0); }, { VM(10); });
    PHASE(u, 1, 1, 1, 0, { STAGE_W(u + 2, 0); }, { VM(10); });
    PHASE(u, 1, 0, 0, 0, { STAGE_W(u + 2, 1); }, { VM(10); });
    PHASE(v, 0, 0, 1, 1, { STAGE_X(u + 2, 1); }, { VM(10); });
    PHASE(v, 0, 1, 0, 1, { STAGE_X(v + 2, 0); }, { VM(10); });
    PHASE(v, 1, 1, 1, 0, { STAGE_W(v + 2, 0); }, { VM(10); });
    PHASE(v, 1, 0, 0, 0, { STAGE_W(v + 2, 1); }, { VM(10); });
  }

  // ---- peeled last iteration (u=nkt-2, v=nkt-1): stage X(v,1) at P1; graded
  //      drains 10,8,-,4,2,0 (unit-traced; identical outstanding counts for
  //      nkt=64 and nkt=32 since the steady state is the same). ----
  {
    const int u = nkt - 2, v = nkt - 1;
    PHASE(u, 0, 0, 1, 1, { STAGE_X(v, 1); }, { VM(10); });
    PHASE(u, 0, 1, 0, 1, {},                 { VM(8);  });
    PHASE(u, 1, 1, 1, 0, {},                 {});
    PHASE(u, 1, 0, 0, 0, {},                 { VM(4);  });
    PHASE(v, 0, 0, 1, 1, {},                 { VM(2);  });
    PHASE(v, 0, 1, 0, 1, {},                 { VM(0);  });
    PHASE(v, 1, 1, 1, 0, {},                 {});
    PHASE(v, 1, 0, 0, 0, {},                 {});
  }

  // ---- epilogue: scale + bias; full tiles store, split tiles atomicAdd ----
  // C/D layout (m89): col = lane&15, row = (lane>>4)*4 + e
  const int erow = (lane >> 4) * 4;
  const int ecol = lane & 15;
  #pragma unroll
  for (int j = 0; j < 4; ++j) {
    const int ocol = col0 + (4 * j + wc) * 16 + ecol;
    const float s  = S[ocol];
    const float bb = (partial && half == 1) ? 0.0f : Bv[ocol];
    #pragma unroll
    for (int ii = 0; ii < 8; ++ii) {
      const int orow = row0 + (2 * ii + wr) * 16 + erow;
      #pragma unroll
      for (int e = 0; e < 4; ++e) {
        const float v = acc[ii][j][e] * s + bb;
        float* dst = &O[(size_t)(orow + e) * N_DIM + ocol];
        if (partial) atomicAdd(dst, v);
        else         *dst = v;
      }
    }
  }
#undef PHASE
#undef VM
#undef STAGE_X
#undef STAGE_W
}

// ---------------- fallback (round-3 kernel, verified) ----------------
#define FB_BM 128
#define FB_BK 32
#define PITCH 40
__global__ __launch_bounds__(256)
void w8a16_fallback_kernel(const float* __restrict__ X, const int* __restrict__ W,
                           const float* __restrict__ S, const float* __restrict__ Bv,
                           float* __restrict__ O)
{
  __shared__ unsigned short As[FB_BM * PITCH];
  __shared__ unsigned short Bs[FB_BM * PITCH];
  const int tid = threadIdx.x, lane = tid & 63, wid = tid >> 6;
  const int wr = wid >> 1, wc = wid & 1;
  const int p = blockIdx.x, xcd = p & 7, seq = p >> 3;
  const int bn_idx = seq >> 3, by_idx = xcd * 8 + (seq & 7);
  const int row0 = by_idx * FB_BM, col0 = bn_idx * FB_BM;
  f32x4 acc[4][4] = {};
  const int st_row = tid >> 1, st_kc = (tid & 1) * 16;
  const float* xsrc = X + (size_t)(row0 + st_row) * K_DIM + st_kc;
  const int*   wsrc = W + (size_t)(col0 + st_row) * K_DIM + st_kc;
  unsigned short* adst = &As[st_row * PITCH + st_kc];
  unsigned short* bdst = &Bs[st_row * PITCH + st_kc];
  const int fr = lane & 15, fk = (lane >> 4) * 8;
  for (int kt = 0; kt < K_DIM; kt += FB_BK) {
    f32x4 a0 = *(const f32x4*)(xsrc + kt);
    f32x4 a1 = *(const f32x4*)(xsrc + kt + 4);
    f32x4 a2 = *(const f32x4*)(xsrc + kt + 8);
    f32x4 a3 = *(const f32x4*)(xsrc + kt + 12);
    i32x4 w0 = *(const i32x4*)(wsrc + kt);
    i32x4 w1 = *(const i32x4*)(wsrc + kt + 4);
    i32x4 w2 = *(const i32x4*)(wsrc + kt + 8);
    i32x4 w3 = *(const i32x4*)(wsrc + kt + 12);
    u16x8 pa0, pa1, pb0, pb1;
    #pragma unroll
    for (int e = 0; e < 4; ++e) {
      pa0[e] = f2bf_rne(a0[e]); pa0[e+4] = f2bf_rne(a1[e]);
      pa1[e] = f2bf_rne(a2[e]); pa1[e+4] = f2bf_rne(a3[e]);
      pb0[e] = i2bf(w0[e]);     pb0[e+4] = i2bf(w1[e]);
      pb1[e] = i2bf(w2[e]);     pb1[e+4] = i2bf(w3[e]);
    }
    __syncthreads();
    *(u16x8*)(adst) = pa0; *(u16x8*)(adst + 8) = pa1;
    *(u16x8*)(bdst) = pb0; *(u16x8*)(bdst + 8) = pb1;
    __syncthreads();
    bf16x8 af2[4], bfr[4];
    #pragma unroll
    for (int i = 0; i < 4; ++i)
      af2[i] = *(const bf16x8*)&As[(wr * 64 + i * 16 + fr) * PITCH + fk];
    #pragma unroll
    for (int j = 0; j < 4; ++j)
      bfr[j] = *(const bf16x8*)&Bs[(wc * 64 + j * 16 + fr) * PITCH + fk];
    #pragma unroll
    for (int i = 0; i < 4; ++i)
      #pragma unroll
      for (int j = 0; j < 4; ++j)
        acc[i][j] = __builtin_amdgcn_mfma_f32_16x16x32_bf16(af2[i], bfr[j], acc[i][j], 0, 0, 0);
  }
  const int erow = (lane >> 4) * 4, ecol = lane & 15;
  #pragma unroll
  for (int j = 0; j < 4; ++j) {
    const int col = col0 + wc * 64 + j * 16 + ecol;
    const float s = S[col], bb = Bv[col];
    #pragma unroll
    for (int i = 0; i < 4; ++i) {
      const int rbase = row0 + wr * 64 + i * 16 + erow;
      #pragma unroll
      for (int e = 0; e < 4; ++e)
        O[(size_t)(rbase + e) * N_DIM + col] = acc[i][j][e] * s + bb;
    }
  }
}

extern "C" void kernel_launch(void* const* d_in, const int* in_sizes, int n_in,
                              void* d_out, int out_size, void* d_ws, size_t ws_size,
                              hipStream_t stream) {
  const float* x  = (const float*)d_in[0];
  const int*   w  = (const int*)d_in[1];
  const float* sc = (const float*)d_in[2];
  const float* bi = (const float*)d_in[3];
  float* out = (float*)d_out;

  const size_t w_elems = (size_t)N_DIM * K_DIM;
  const size_t x_elems = (size_t)M_DIM * K_DIM;
  const size_t need = (w_elems + x_elems) * sizeof(unsigned short);

  if (ws_size >= need) {
    unsigned short* Wb = (unsigned short*)d_ws;
    unsigned short* Xb = Wb + w_elems;
    zero_partial_kernel<<<1024, 256, 0, stream>>>(out);
    dequant_w_kernel<<<2048, 256, 0, stream>>>(w, Wb);
    conv_x_kernel<<<2048, 256, 0, stream>>>(x, Xb);
    // grid: 1280 full-K blocks + 192 half-K blocks (last 96 tiles split in 2)
    const int grid = FULL_TILES + 2 * (NTILES - FULL_TILES);  // 1472
    w8a16_main_kernel<<<grid, 512, 0, stream>>>(Xb, Wb, sc, bi, out);
  } else {
    const int grid = (M_DIM / FB_BM) * (N_DIM / FB_BM);
    w8a16_fallback_kernel<<<grid, 256, 0, stream>>>(x, w, sc, bi, out);
  }
}